// Round 1
// baseline (121.117 us; speedup 1.0000x reference)
//
#include <hip/hip_runtime.h>
#include <hip/hip_bf16.h>

// LiftSplatShoot collapsed form:
//   out[b,n,i,p,d] = a_i[b,n,p] * depths[d] + E[b,n,i,3]
//   a_i[p] = sum_j E[i,j] * (Kinv[j,:] . [x,y,1]) * softmax_HW(feat)[j,p]
// B=2,N=6,C=3,H=64,W=176,D=64

#define BN   12
#define CCH  3
#define HH   64
#define WW   176
#define HWSZ (HH * WW)   // 11264
#define DD   64
#define PIX  16          // pixels per block in main kernel
#define TILES (HWSZ / PIX) // 704

// ---------------- Kernel 1: per-(bn,c) softmax stats --------------------
// 36 blocks, 256 threads. Row of 11264 fp32 = 2816 float4 = 11 float4/thread.
__global__ __launch_bounds__(256) void lss_softmax_stats(
    const float* __restrict__ feat, float* __restrict__ mx_out,
    float* __restrict__ invsum_out) {
  const int row = blockIdx.x;  // 0..35  (bn*3 + c)
  const int t = threadIdx.x;
  const float4* rp = (const float4*)(feat + (size_t)row * HWSZ);

  float4 v[11];
  float m = -3.4e38f;
#pragma unroll
  for (int k = 0; k < 11; ++k) {
    v[k] = rp[t + 256 * k];
    m = fmaxf(m, fmaxf(fmaxf(v[k].x, v[k].y), fmaxf(v[k].z, v[k].w)));
  }
  // wave64 max reduce
#pragma unroll
  for (int off = 32; off > 0; off >>= 1) m = fmaxf(m, __shfl_down(m, off, 64));

  __shared__ float smax[4];
  __shared__ float ssum[4];
  const int wave = t >> 6, lane = t & 63;
  if (lane == 0) smax[wave] = m;
  __syncthreads();
  if (t == 0)
    smax[0] = fmaxf(fmaxf(smax[0], smax[1]), fmaxf(smax[2], smax[3]));
  __syncthreads();
  m = smax[0];

  float s = 0.f;
#pragma unroll
  for (int k = 0; k < 11; ++k) {
    s += __expf(v[k].x - m) + __expf(v[k].y - m) + __expf(v[k].z - m) +
         __expf(v[k].w - m);
  }
#pragma unroll
  for (int off = 32; off > 0; off >>= 1) s += __shfl_down(s, off, 64);
  if (lane == 0) ssum[wave] = s;
  __syncthreads();
  if (t == 0) {
    mx_out[row] = m;
    invsum_out[row] = 1.0f / (ssum[0] + ssum[1] + ssum[2] + ssum[3]);
  }
}

// ---------------- Kernel 2: main write kernel ---------------------------
// grid = BN*TILES blocks of 256 threads. Block handles 16 consecutive pixels
// of one (b,n): phase A computes s_c & a_i into LDS, phase B streams the
// 16 pix * 3 ch * 64 depth fp32 outputs as float4 (fully coalesced per wave).
__global__ __launch_bounds__(256) void lss_main(
    const float* __restrict__ feat, const float* __restrict__ intr,
    const float* __restrict__ extr, const float* __restrict__ depths,
    const float* __restrict__ mx, const float* __restrict__ invsum,
    float* __restrict__ out) {
  const int blk = blockIdx.x;
  const int bn = blk / TILES;
  const int tile = blk - bn * TILES;
  const int p0 = tile * PIX;
  const int t = threadIdx.x;

  __shared__ float s_s[PIX][4];  // rays_c * prob_c
  __shared__ float s_a[PIX][4];  // a_i

  // 3x3 inverse of intrinsics upper-left block (uniform per block)
  const float* Kp = intr + bn * 16;
  const float a = Kp[0], b = Kp[1], c = Kp[2];
  const float d = Kp[4], e = Kp[5], f = Kp[6];
  const float g = Kp[8], h = Kp[9], i9 = Kp[10];
  const float A0 = e * i9 - f * h;
  const float B0 = -(d * i9 - f * g);
  const float C0 = d * h - e * g;
  const float invdet = 1.0f / (a * A0 + b * B0 + c * C0);
  const float inv00 = A0 * invdet, inv01 = -(b * i9 - c * h) * invdet,
              inv02 = (b * f - c * e) * invdet;
  const float inv10 = B0 * invdet, inv11 = (a * i9 - c * g) * invdet,
              inv12 = -(a * f - c * d) * invdet;
  const float inv20 = C0 * invdet, inv21 = -(a * h - b * g) * invdet,
              inv22 = (a * e - b * d) * invdet;

  const float* Ep = extr + bn * 16;

  if (t < 48) {
    const int cc = t >> 4;     // channel 0..2
    const int pl = t & 15;     // pixel in tile
    const int p = p0 + pl;
    const float fv = feat[((size_t)bn * CCH + cc) * HWSZ + p];
    const float prob = __expf(fv - mx[bn * CCH + cc]) * invsum[bn * CCH + cc];
    const float x = (float)(p % WW);
    const float y = (float)(p / WW);
    float ray;
    if (cc == 0)      ray = inv00 * x + inv01 * y + inv02;
    else if (cc == 1) ray = inv10 * x + inv11 * y + inv12;
    else              ray = inv20 * x + inv21 * y + inv22;
    s_s[pl][cc] = ray * prob;
  }
  __syncthreads();
  if (t < 48) {
    const int ii = t >> 4;
    const int pl = t & 15;
    s_a[pl][ii] = Ep[ii * 4 + 0] * s_s[pl][0] + Ep[ii * 4 + 1] * s_s[pl][1] +
                  Ep[ii * 4 + 2] * s_s[pl][2];
  }
  __syncthreads();

  const int pl = t >> 4;   // pixel in tile
  const int dq = t & 15;   // depth quad
  const int p = p0 + pl;
  const float4 dep = ((const float4*)depths)[dq];
#pragma unroll
  for (int ii = 0; ii < 3; ++ii) {
    const float av = s_a[pl][ii];
    const float tr = Ep[ii * 4 + 3];
    float4 o;
    o.x = av * dep.x + tr;
    o.y = av * dep.y + tr;
    o.z = av * dep.z + tr;
    o.w = av * dep.w + tr;
    ((float4*)out)[(((size_t)bn * CCH + ii) * HWSZ + p) * (DD / 4) + dq] = o;
  }
}

extern "C" void kernel_launch(void* const* d_in, const int* in_sizes, int n_in,
                              void* d_out, int out_size, void* d_ws,
                              size_t ws_size, hipStream_t stream) {
  const float* feat = (const float*)d_in[0];    // (12,3,11264)
  const float* intr = (const float*)d_in[1];    // (2,6,4,4)
  const float* extr = (const float*)d_in[2];    // (2,6,4,4)
  // d_in[3] = xy1 (recomputed analytically), d_in[4] = depths
  const float* depths = (const float*)d_in[4];  // (64,)
  float* out = (float*)d_out;

  float* mx = (float*)d_ws;          // 36 floats
  float* invsum = mx + 64;           // 36 floats (64-offset for alignment)

  lss_softmax_stats<<<BN * CCH, 256, 0, stream>>>(feat, mx, invsum);
  lss_main<<<BN * TILES, 256, 0, stream>>>(feat, intr, extr, depths, mx,
                                           invsum, out);
}